// Round 1
// baseline (330.354 us; speedup 1.0000x reference)
//
#include <hip/hip_runtime.h>

#define Mm 160000
#define Nn 10000

typedef __attribute__((ext_vector_type(8))) short short8;
typedef __attribute__((ext_vector_type(4))) short short4v;
typedef __attribute__((ext_vector_type(4))) float float4v;

__device__ __forceinline__ short f2bf(float f) {
  // round-to-nearest-even fp32 -> bf16 (inputs are finite, no NaN handling)
  unsigned u = __builtin_bit_cast(unsigned, f);
  u = (u + 0x7FFFu + ((u >> 16) & 1u)) >> 16;
  return (short)u;
}

// Wv [k=256][n=256] fp32 -> Wv_bt [n][k] bf16 (tiny, one-shot)
__global__ __launch_bounds__(256) void prep_k(const float* __restrict__ Wv,
                                              short* __restrict__ bt) {
  const int n = blockIdx.x, k = threadIdx.x;
  bt[n * 256 + k] = f2bf(Wv[k * 256 + n]);
}

// One block = 64 rows x 256 cols of v = x@Wv, K=256.
// Wave w (0..3) owns head w (cols 64w..64w+63) -> per-head LayerNorm in-wave.
// B fragments are read straight from L2 (bt is a 128 KB resident constant):
// no Bt LDS tile, no Bt staging barrier. A (the only LDS user) is
// double-buffered (2 x 9.2 KB) with register prefetch -> 1 barrier per K-step.
__global__ __launch_bounds__(256, 4) void gemm_ln(const float* __restrict__ x,
                                                  const short* __restrict__ bt,
                                                  const float* __restrict__ gamma,
                                                  const float* __restrict__ beta,
                                                  float* __restrict__ out) {
  __shared__ short A[2][64][72];  // [buf][row][k], +8 pad: 2-way max on reads
  const int t = threadIdx.x;
  const int m0 = blockIdx.x * 64;
  const int w = t >> 6;   // wave = head
  const int l = t & 63;
  const int c16 = l & 15;
  const int q8 = (l >> 4) * 8;

  float4v acc[4][4];
#pragma unroll
  for (int i = 0; i < 4; ++i)
#pragma unroll
    for (int j = 0; j < 4; ++j) acc[i][j] = (float4v){0.f, 0.f, 0.f, 0.f};

  const int ar = t >> 4, ak = (t & 15) * 4;  // A staging: 16 lanes cover a row
  const float* xrow = x + (size_t)(m0 + ar) * 256 + ak;        // +j*4096 +k0
  const short* brow = bt + (size_t)(w * 64 + c16) * 256 + q8;  // +j*4096 +k0 +c*32

  // prologue: stage k0=0 into buffer 0
  float4 xr[4];
#pragma unroll
  for (int j = 0; j < 4; ++j) xr[j] = *(const float4*)(xrow + (size_t)j * 4096);
#pragma unroll
  for (int j = 0; j < 4; ++j) {
    short4v s;
    s.x = f2bf(xr[j].x); s.y = f2bf(xr[j].y); s.z = f2bf(xr[j].z); s.w = f2bf(xr[j].w);
    *(short4v*)&A[0][ar + j * 16][ak] = s;
  }
  __syncthreads();

#pragma unroll
  for (int it = 0; it < 4; ++it) {
    const int k0 = it * 64;
    const int cur = it & 1;
    // issue next A-tile global loads early (hidden under MFMA below)
    if (it < 3) {
#pragma unroll
      for (int j = 0; j < 4; ++j)
        xr[j] = *(const float4*)(xrow + (size_t)j * 4096 + k0 + 64);
    }
    // compute from A[cur]; B fragments direct from L2
#pragma unroll
    for (int c = 0; c < 2; ++c) {
      short8 af[4], bf[4];
#pragma unroll
      for (int i = 0; i < 4; ++i)
        af[i] = *(const short8*)&A[cur][i * 16 + c16][c * 32 + q8];
#pragma unroll
      for (int j = 0; j < 4; ++j)
        bf[j] = *(const short8*)(brow + j * 4096 + k0 + c * 32);
#pragma unroll
      for (int i = 0; i < 4; ++i)
#pragma unroll
        for (int j = 0; j < 4; ++j)
          acc[i][j] = __builtin_amdgcn_mfma_f32_16x16x32_bf16(af[i], bf[j],
                                                              acc[i][j], 0, 0, 0);
    }
    // convert + write next buffer, single barrier per K-step
    if (it < 3) {
#pragma unroll
      for (int j = 0; j < 4; ++j) {
        short4v s;
        s.x = f2bf(xr[j].x); s.y = f2bf(xr[j].y); s.z = f2bf(xr[j].z); s.w = f2bf(xr[j].w);
        *(short4v*)&A[cur ^ 1][ar + j * 16][ak] = s;
      }
      __syncthreads();
    }
  }

  // Epilogue: per-head LayerNorm + scatter.
  // C/D layout: col = l&15 (within 16-tile), row = (l>>4)*4 + reg.
  float g[4], be[4];
#pragma unroll
  for (int j = 0; j < 4; ++j) {
    g[j] = gamma[j * 16 + c16];
    be[j] = beta[j * 16 + c16];
  }
  const int q4 = (l >> 4) * 4;
#pragma unroll
  for (int i = 0; i < 4; ++i) {
#pragma unroll
    for (int reg = 0; reg < 4; ++reg) {
      float s1 = acc[i][0][reg] + acc[i][1][reg] + acc[i][2][reg] + acc[i][3][reg];
      float s2 = acc[i][0][reg] * acc[i][0][reg] + acc[i][1][reg] * acc[i][1][reg] +
                 acc[i][2][reg] * acc[i][2][reg] + acc[i][3][reg] * acc[i][3][reg];
      s1 += __shfl_xor(s1, 1); s2 += __shfl_xor(s2, 1);
      s1 += __shfl_xor(s1, 2); s2 += __shfl_xor(s2, 2);
      s1 += __shfl_xor(s1, 4); s2 += __shfl_xor(s2, 4);
      s1 += __shfl_xor(s1, 8); s2 += __shfl_xor(s2, 8);
      const float mu = s1 * (1.f / 64.f);
      const float var = s2 * (1.f / 64.f) - mu * mu;
      const float inv = rsqrtf(var + 1e-5f);
      const int m = m0 + i * 16 + q4 + reg;
      const int b = m / Nn;
      const int n = m - b * Nn;
      const size_t obase = (size_t)(n & 15) * 2560000u +
                           (size_t)(b * 625 + (n >> 4)) * 256u + w * 64 + c16;
#pragma unroll
      for (int j = 0; j < 4; ++j)
        out[obase + j * 16] = (acc[i][j][reg] - mu) * inv * g[j] + be[j];
    }
  }
}

extern "C" void kernel_launch(void* const* d_in, const int* in_sizes, int n_in,
                              void* d_out, int out_size, void* d_ws, size_t ws_size,
                              hipStream_t stream) {
  const float* x = (const float*)d_in[0];
  const float* Wv = (const float*)d_in[4];
  const float* gamma = (const float*)d_in[5];
  const float* beta = (const float*)d_in[6];
  float* out = (float*)d_out;
  short* wv_bt = (short*)d_ws;  // 256*256 bf16 = 128 KB

  prep_k<<<256, 256, 0, stream>>>(Wv, wv_bt);
  gemm_ln<<<Mm / 64, 256, 0, stream>>>(x, wv_bt, gamma, beta, out);
}